// Round 8
// baseline (341.561 us; speedup 1.0000x reference)
//
#include <hip/hip_runtime.h>
#include <stdint.h>
#include <math.h>

typedef __attribute__((ext_vector_type(8))) short bf16x8;
typedef __attribute__((ext_vector_type(4))) short v4s;
typedef __attribute__((ext_vector_type(4))) float f32x4;
typedef __attribute__((ext_vector_type(4))) unsigned short u16x4;
typedef __attribute__((ext_vector_type(2))) unsigned int u32x2;

#define MFMA16(a,b,c)   __builtin_amdgcn_mfma_f32_16x16x32_bf16((a),(b),(c),0,0,0)
#define MFMA16K(a,b,c)  __builtin_amdgcn_mfma_f32_16x16x16bf16_1k((a),(b),(c),0,0,0)

static __device__ __forceinline__ void gld_lds16(const void* g, void* l) {
  __builtin_amdgcn_global_load_lds(
      (const __attribute__((address_space(1))) unsigned int*)g,
      (__attribute__((address_space(3))) unsigned int*)l,
      16, 0, 0);
}

static __device__ __forceinline__ unsigned short f2bf(float f) {
  unsigned int u = __builtin_bit_cast(unsigned int, f);
  return (unsigned short)((u + 0x8000u) >> 16);
}

// Single-launch fp32->bf16 for x (8M) + 4 weights (1M each), grid-stride over float4s.
__global__ __launch_bounds__(256) void cvt_all_kernel(
    const float* __restrict__ x,
    const float* __restrict__ w0, const float* __restrict__ w1,
    const float* __restrict__ w2, const float* __restrict__ w3,
    unsigned short* __restrict__ xb, unsigned short* __restrict__ wb)
{
  int i = blockIdx.x * 256 + threadIdx.x;
  const int stride = gridDim.x * 256;
  for (; i < 3145728; i += stride) {          // 2M x-f4 + 4 x 256K w-f4
    const float* src; unsigned short* dst; int off;
    if (i < 2097152) { src = x; dst = xb; off = i; }
    else {
      int j = i - 2097152;
      int seg = j >> 18;                      // 262144 float4 per weight
      off = j & 262143;
      src = (seg == 0) ? w0 : (seg == 1) ? w1 : (seg == 2) ? w2 : w3;
      dst = wb + (size_t)seg * 1048576;
    }
    float4 v = ((const float4*)src)[off];
    u16x4 o;
    o.x = f2bf(v.x); o.y = f2bf(v.y); o.z = f2bf(v.z); o.w = f2bf(v.w);
    ((u16x4*)dst)[off] = o;
  }
}

// C = A[M,K] * Bt[N,K]^T, A/Bt bf16, K=1024, 128x128 tile.
// MODE 0: C bf16 head-split [b,h,s,d] (b=row>>11).
// MODE 1: C fp32 row-major [M,1024].
// MODE 2: C bf16 head-split TRANSPOSED [b,h,d,s] (for V).
// MODE 3: like MODE 0 but scaled by log2(e)/8 (for Q: folds softmax scale).
template<int MODE, typename CT>
__device__ __forceinline__ void gemm_bt_tile(const unsigned short* __restrict__ A,
                                             const unsigned short* __restrict__ Bt,
                                             CT* __restrict__ C,
                                             int m0, int n0)
{
  __shared__ __align__(16) unsigned short As[128*32];
  __shared__ __align__(16) unsigned short Bs[128*32];
  const int tid  = threadIdx.x;
  const int w    = tid >> 6, lane = tid & 63;
  const int quad = lane >> 4, c0 = lane & 15;
  const int wm   = w >> 1, wn = w & 1;

  const unsigned short* ga[2];
  const unsigned short* gb[2];
  int ldsoff[2];
  #pragma unroll
  for (int i = 0; i < 2; ++i) {
    int f = i*4096 + w*1024 + lane*16;
    int r = f >> 6;
    int q = (f >> 4) & 3;
    ga[i] = A  + (m0 + r)*1024 + q*8;
    gb[i] = Bt + (n0 + r)*1024 + q*8;
    ldsoff[i] = i*4096 + w*1024;
  }

  int aAddr[4], bAddr[4];
  #pragma unroll
  for (int t = 0; t < 4; ++t) {
    aAddr[t] = (wm*64 + t*16 + c0)*64 + quad*16;
    bAddr[t] = (wn*64 + t*16 + c0)*64 + quad*16;
  }

  f32x4 acc[4][4];
  #pragma unroll
  for (int i = 0; i < 4; ++i)
    #pragma unroll
    for (int j = 0; j < 4; ++j)
      acc[i][j] = (f32x4){0.f, 0.f, 0.f, 0.f};

  for (int kt = 0; kt < 32; ++kt) {
    __syncthreads();
    #pragma unroll
    for (int i = 0; i < 2; ++i) {
      gld_lds16(ga[i] + kt*32, (char*)As + ldsoff[i]);
      gld_lds16(gb[i] + kt*32, (char*)Bs + ldsoff[i]);
    }
    __syncthreads();

    bf16x8 af[4], bfr[4];
    #pragma unroll
    for (int t = 0; t < 4; ++t) af[t]  = *(const bf16x8*)((const char*)As + aAddr[t]);
    #pragma unroll
    for (int t = 0; t < 4; ++t) bfr[t] = *(const bf16x8*)((const char*)Bs + bAddr[t]);

    #pragma unroll
    for (int mt = 0; mt < 4; ++mt)
      #pragma unroll
      for (int nt = 0; nt < 4; ++nt)
        acc[mt][nt] = MFMA16(af[mt], bfr[nt], acc[mt][nt]);
  }

  const float scl = (MODE == 3) ? 0.1803368801f : 1.0f;  // log2(e)/8
  #pragma unroll
  for (int mt = 0; mt < 4; ++mt) {
    #pragma unroll
    for (int nt = 0; nt < 4; ++nt) {
      if (MODE == 2) {
        u16x4 pk;
        #pragma unroll
        for (int r = 0; r < 4; ++r) pk[r] = f2bf(acc[mt][nt][r]);
        int s0 = m0 + wm*64 + mt*16 + quad*4;
        int gc = n0 + wn*64 + nt*16 + c0;
        int b = s0 >> 11, ss = s0 & 2047;
        int h = gc >> 6, d = gc & 63;
        *(u16x4*)((unsigned short*)C + (size_t)(((b << 4) + h)*64 + d)*2048 + ss) = pk;
      } else {
        #pragma unroll
        for (int r = 0; r < 4; ++r) {
          int gr = m0 + wm*64 + mt*16 + quad*4 + r;
          int gc = n0 + wn*64 + nt*16 + c0;
          if (MODE == 0 || MODE == 3) {
            int b = gr >> 11, s = gr & 2047;
            int h = gc >> 6, d = gc & 63;
            ((unsigned short*)C)[(((b << 4) + h)*2048 + s)*64 + d] = f2bf(acc[mt][nt][r] * scl);
          } else {
            ((float*)C)[gr*1024 + gc] = acc[mt][nt][r];
          }
        }
      }
    }
  }
}

__global__ __launch_bounds__(256) void qkv_kernel(
    const unsigned short* __restrict__ X,
    const unsigned short* __restrict__ WQ, const unsigned short* __restrict__ WK,
    const unsigned short* __restrict__ WV,
    unsigned short* __restrict__ Q, unsigned short* __restrict__ K,
    unsigned short* __restrict__ V)
{
  if (blockIdx.z == 2) {
    gemm_bt_tile<2>(X, WV, V, blockIdx.x*128, blockIdx.y*128);
  } else if (blockIdx.z == 0) {
    gemm_bt_tile<3>(X, WQ, Q, blockIdx.x*128, blockIdx.y*128);  // pre-scaled Q
  } else {
    gemm_bt_tile<0>(X, WK, K, blockIdx.x*128, blockIdx.y*128);
  }
}

__global__ __launch_bounds__(256) void proj_kernel(
    const unsigned short* __restrict__ A,
    const unsigned short* __restrict__ WO,
    float* __restrict__ C)
{
  gemm_bt_tile<1>(A, WO, C, blockIdx.x*128, blockIdx.y*128);
}

// Flash attention, causal. Q (pre-scaled by log2e/8) / K bf16 [bh,s,64];
// V TRANSPOSED bf16 [bh,64,s]. O bf16 [b,s,1024].
// Block = 64 Q rows (4 waves x 16), 256 threads. Grid (16, BH): block bx handles
// the q-chunk PAIR {31-bx, bx} = exactly 17 half-tiles -> balanced, and
// 1024 blocks = 4 blocks/CU (2x the occupancy of the 128-row version).
// S^T = K Q^T, in-register P (16x16x16 PV), K register prefetch,
// V^T double-buffered via global_load_lds, one barrier per tile.
__global__ __launch_bounds__(256, 4) void attn_kernel(
    const unsigned short* __restrict__ Q,
    const unsigned short* __restrict__ K,
    const unsigned short* __restrict__ Vt,
    unsigned short* __restrict__ O)
{
  __shared__ __align__(16) unsigned short VtL[2][64*128];  // V^T tiles, chunk-swizzled

  const int tid  = threadIdx.x;
  const int w    = tid >> 6, lane = tid & 63;
  const int quad = lane >> 4, c0 = lane & 15;
  const int bx = blockIdx.x, bh = blockIdx.y;

  const unsigned short* Qh = Q  + (size_t)bh*2048*64;
  const unsigned short* Kh = K  + (size_t)bh*2048*64;
  const unsigned short* Vh = Vt + (size_t)bh*64*2048;

  // V^T staging: LDS chunk (row r, chunk q) receives global chunk q^(r&15)
  const unsigned short* vga[4];
  int vldsoff[4];
  #pragma unroll
  for (int i = 0; i < 4; ++i) {
    int cid = i*256 + tid;
    int r = cid >> 4, q = cid & 15;
    int gq = q ^ (r & 15);
    vga[i] = Vh + (size_t)r*2048 + gq*8;
    vldsoff[i] = i*4096 + w*1024;
  }

  const int b = bh >> 4, h = bh & 15;
  bf16x8 kreg[8][2];   // current K tile in registers

  #define ATTN_MK_BODY(mk, Vb, DIAG)                                              \
  {                                                                               \
    f32x4 s0 = (f32x4){0.f,0.f,0.f,0.f};                                          \
    _Pragma("unroll")                                                             \
    for (int ks = 0; ks < 2; ++ks)                                                \
      s0 = MFMA16(kreg[mk][ks], qf[ks], s0);                                      \
    if (DIAG) {                                                                   \
      _Pragma("unroll")                                                           \
      for (int r = 0; r < 4; ++r) {                                               \
        int kk = (mk)*16 + quad*4 + r;                                            \
        if (kk > qql) s0[r] = -1e30f;                                             \
      }                                                                           \
    }                                                                             \
    float p0 = __builtin_amdgcn_exp2f(s0[0]), p1 = __builtin_amdgcn_exp2f(s0[1]); \
    float p2 = __builtin_amdgcn_exp2f(s0[2]), p3 = __builtin_amdgcn_exp2f(s0[3]); \
    l_r += (p0 + p1) + (p2 + p3);                                                 \
    u32x2 a0;                                                                     \
    a0.x = __builtin_amdgcn_perm(__builtin_bit_cast(unsigned int, p1),            \
                                 __builtin_bit_cast(unsigned int, p0), 0x07060302u); \
    a0.y = __builtin_amdgcn_perm(__builtin_bit_cast(unsigned int, p3),            \
                                 __builtin_bit_cast(unsigned int, p2), 0x07060302u); \
    v4s pa0 = __builtin_bit_cast(v4s, a0);                                        \
    _Pragma("unroll")                                                             \
    for (int dt = 0; dt < 4; ++dt) {                                              \
      int vr = dt*16 + c0;                                                        \
      int p  = 2*(mk) + (quad >> 1);                                              \
      v4s vb = *(const v4s*)((const char*)(Vb) + vr*256 + ((p ^ c0) * 16) + (quad & 1)*8); \
      o_[dt] = MFMA16K(pa0, vb, o_[dt]);                                          \
    }                                                                             \
  }

  for (int pi = 0; pi < 2; ++pi) {
    const int qc = pi ? bx : 31 - bx;   // q-chunk (64 rows); pair sums to 17 tiles
    const int D  = qc >> 1;             // diagonal k-tile index
    const int qql = (qc & 1)*64 + w*16 + c0;   // q position local to tile D

    // Q B-frag: B[n=q=c0][k=d=quad*8+j], rows qc*64 + w*16 + c0
    bf16x8 qf[2];
    #pragma unroll
    for (int ks = 0; ks < 2; ++ks)
      qf[ks] = *(const bf16x8*)(Qh + (qc*64 + w*16 + c0)*64 + ks*32 + quad*8);

    f32x4 o_[4];
    float l_r = 0.f;
    #pragma unroll
    for (int dt = 0; dt < 4; ++dt) o_[dt] = (f32x4){0.f, 0.f, 0.f, 0.f};

    __syncthreads();   // prior pass's LDS readers done
    #pragma unroll
    for (int i = 0; i < 4; ++i)
      gld_lds16(vga[i], (char*)VtL[0] + vldsoff[i]);
    #pragma unroll
    for (int mk = 0; mk < 8; ++mk)
      #pragma unroll
      for (int ks = 0; ks < 2; ++ks)
        kreg[mk][ks] = *(const bf16x8*)(Kh + (mk*16 + c0)*64 + ks*32 + quad*8);

    for (int kt = 0; kt < D; ++kt) {
      __syncthreads();   // drains V DMA + K prefetch; readers of next buf done
      #pragma unroll
      for (int i = 0; i < 4; ++i)
        gld_lds16(vga[i] + (kt+1)*128, (char*)VtL[(kt+1)&1] + vldsoff[i]);
      const unsigned short* Vb = VtL[kt & 1];
      #pragma unroll
      for (int mk = 0; mk < 8; ++mk)
        ATTN_MK_BODY(mk, Vb, false)
      #pragma unroll
      for (int mk = 0; mk < 8; ++mk)
        #pragma unroll
        for (int ks = 0; ks < 2; ++ks)
          kreg[mk][ks] = *(const bf16x8*)(Kh + ((kt+1)*128 + mk*16 + c0)*64 + ks*32 + quad*8);
    }

    // diagonal tile: mask; wave w only needs mk < (qc&1)*4 + w + 1
    {
      __syncthreads();
      const unsigned short* Vb = VtL[D & 1];
      const int mkEnd = ((qc & 1) << 2) + w + 1;
      #pragma unroll
      for (int mk = 0; mk < 8; ++mk)
        if (mk < mkEnd)
          ATTN_MK_BODY(mk, Vb, true)
    }

    // reduce l across quads (16 lanes sharing c0 hold partial sums for row c0)
    l_r += __shfl_xor(l_r, 16);
    l_r += __shfl_xor(l_r, 32);

    // epilogue: O C-layout row = quad*4+r (within wave's 16 q), col d = dt*16+c0
    #pragma unroll
    for (int r = 0; r < 4; ++r) {
      float l = __shfl(l_r, quad*4 + r);
      float inv = 1.0f / l;
      int srow = qc*64 + w*16 + quad*4 + r;
      #pragma unroll
      for (int dt = 0; dt < 4; ++dt) {
        int col = h*64 + dt*16 + c0;
        O[((size_t)b*2048 + srow)*1024 + col] = f2bf(o_[dt][r] * inv);
      }
    }
  }
  #undef ATTN_MK_BODY
}

extern "C" void kernel_launch(void* const* d_in, const int* in_sizes, int n_in,
                              void* d_out, int out_size, void* d_ws, size_t ws_size,
                              hipStream_t stream) {
  const float* xf  = (const float*)d_in[0];
  const float* wqf = (const float*)d_in[1];
  const float* wkf = (const float*)d_in[2];
  const float* wvf = (const float*)d_in[3];
  const float* wof = (const float*)d_in[4];
  float* out = (float*)d_out;
  unsigned short* ws = (unsigned short*)d_ws;

  const bool fused = ws_size >= (size_t)58720256;  // 56 MB

  if (fused) {
    unsigned short* xb  = ws;                    // 8M elems; aliased by Ow after qkv
    unsigned short* wb  = ws + 8388608;          // wq|wk|wv|wo, 1M each
    unsigned short* Kw  = ws + 12582912;
    unsigned short* Vw  = ws + 20971520;
    unsigned short* Ow  = xb;
    unsigned short* Qd  = (unsigned short*)out;  // bf16 Q scratch in fp32 out region

    cvt_all_kernel<<<3072, 256, 0, stream>>>(xf, wqf, wkf, wvf, wof, xb, wb);

    qkv_kernel <<<dim3(64, 8, 3), 256, 0, stream>>>(xb, wb, wb + 1048576, wb + 2097152,
                                                    Qd, Kw, Vw);
    attn_kernel<<<dim3(16, 64),   256, 0, stream>>>(Qd, Kw, Vw, Ow);
    proj_kernel<<<dim3(64, 8),    256, 0, stream>>>(Ow, wb + 3145728, out);
  } else {
    unsigned short* xb  = ws;
    unsigned short* wb  = ws + 8388608;
    unsigned short* Kw  = ws + 12582912;
    unsigned short* Vw  = ws + 14680064;
    unsigned short* Ow  = ws + 16777216;

    cvt_all_kernel<<<3072, 256, 0, stream>>>(xf, wqf, wkf, wvf, wof, xb, wb);

    for (int b = 0; b < 4; ++b) {
      const unsigned short* xbb = xb  + (size_t)b * 2048 * 1024;
      float*               outb = out + (size_t)b * 2048 * 1024;
      unsigned short*        Qd = (unsigned short*)outb;
      qkv_kernel <<<dim3(16, 8, 3), 256, 0, stream>>>(xbb, wb, wb + 1048576, wb + 2097152,
                                                      Qd, Kw, Vw);
      attn_kernel<<<dim3(16, 16),   256, 0, stream>>>(Qd, Kw, Vw, Ow);
      proj_kernel<<<dim3(16, 8),    256, 0, stream>>>(Ow, wb + 3145728, outb);
    }
  }
}